// Round 1
// baseline (150.152 us; speedup 1.0000x reference)
//
#include <hip/hip_runtime.h>
#include <hip/hip_bf16.h>

typedef short bf16x8 __attribute__((ext_vector_type(8)));
typedef float f32x4 __attribute__((ext_vector_type(4)));
typedef unsigned short u16x4 __attribute__((ext_vector_type(4)));

#define B_ 16
#define T_ 2048
#define C_ 1024
#define D_ 128
#define M_ (B_ * T_)

static __device__ __forceinline__ unsigned short f2bf(float f) {
    unsigned int u = __builtin_bit_cast(unsigned int, f);
    unsigned int r = (u + 0x7fffu + ((u >> 16) & 1u)) >> 16;
    return (unsigned short)r;
}

// ---------------------------------------------------------------------------
// Kernel 0: W [1024][128] fp32  ->  Wt [128][1024] bf16   (x3, concatenated)
// ---------------------------------------------------------------------------
__global__ void wt_kernel(const float* __restrict__ Wq, const float* __restrict__ Wk,
                          const float* __restrict__ Wv, unsigned short* __restrict__ Wt) {
    int idx = blockIdx.x * 256 + threadIdx.x;   // 3 * 131072 total
    int o   = idx >> 17;
    int rem = idx & 131071;
    int k   = rem >> 7;
    int n   = rem & 127;
    const float* W = (o == 0) ? Wq : (o == 1) ? Wk : Wv;
    Wt[o * (D_ * C_) + n * C_ + k] = f2bf(W[rem]);
}

// ---------------------------------------------------------------------------
// Kernel 1: fused QKV projection.  BM=128, BK=32, 8 waves (2x... 4 row x 2 col)
//   Q [M][128] bf16 (scaled by D^-0.5), K [M][128] bf16, Vt [B][128][2048] bf16
// ---------------------------------------------------------------------------
#define APAD 40   // 32 + 8 bf16 pad -> 80B row stride, 2-way bank conflict (free)

__launch_bounds__(512, 1)
__global__ void qkv_kernel(const float* __restrict__ x, const unsigned short* __restrict__ Wt,
                           unsigned short* __restrict__ Q, unsigned short* __restrict__ K,
                           unsigned short* __restrict__ Vt) {
    __shared__ unsigned short Alds[128 * APAD];
    __shared__ unsigned short Blds[3][128 * APAD];

    const int tid  = threadIdx.x;
    const int lane = tid & 63;
    const int w    = tid >> 6;   // 0..7
    const int wr   = w >> 1;     // 0..3 (32-row group)
    const int wc   = w & 1;      // 0..1 (64-col group)
    const int lr   = lane & 15;
    const int lk   = lane >> 4;  // 0..3
    const int m0   = blockIdx.x * 128;

    f32x4 acc[3][2][4] = {};

    const int sr  = tid >> 2;          // 0..127 staging row
    const int sc8 = (tid & 3) * 8;     // 0,8,16,24

    for (int k0 = 0; k0 < C_; k0 += 32) {
        // stage A (x fp32 -> bf16)
        {
            const float* src = x + (size_t)(m0 + sr) * C_ + k0 + sc8;
            float4 f0 = *(const float4*)src;
            float4 f1 = *(const float4*)(src + 4);
            bf16x8 v;
            v[0] = (short)f2bf(f0.x); v[1] = (short)f2bf(f0.y);
            v[2] = (short)f2bf(f0.z); v[3] = (short)f2bf(f0.w);
            v[4] = (short)f2bf(f1.x); v[5] = (short)f2bf(f1.y);
            v[6] = (short)f2bf(f1.z); v[7] = (short)f2bf(f1.w);
            *(bf16x8*)&Alds[sr * APAD + sc8] = v;
        }
        // stage B x3 (Wt already bf16, [n][k] layout)
#pragma unroll
        for (int o = 0; o < 3; ++o) {
            bf16x8 v = *(const bf16x8*)(Wt + o * (D_ * C_) + sr * C_ + k0 + sc8);
            *(bf16x8*)&Blds[o][sr * APAD + sc8] = v;
        }
        __syncthreads();

        bf16x8 a0 = *(bf16x8*)&Alds[(wr * 32 +      lr) * APAD + lk * 8];
        bf16x8 a1 = *(bf16x8*)&Alds[(wr * 32 + 16 + lr) * APAD + lk * 8];
#pragma unroll
        for (int o = 0; o < 3; ++o) {
#pragma unroll
            for (int nb = 0; nb < 4; ++nb) {
                bf16x8 b = *(bf16x8*)&Blds[o][(wc * 64 + nb * 16 + lr) * APAD + lk * 8];
                acc[o][0][nb] = __builtin_amdgcn_mfma_f32_16x16x32_bf16(a0, b, acc[o][0][nb], 0, 0, 0);
                acc[o][1][nb] = __builtin_amdgcn_mfma_f32_16x16x32_bf16(a1, b, acc[o][1][nb], 0, 0, 0);
            }
        }
        __syncthreads();
    }

    // epilogue. D layout: row = lk*4 + reg, col = lr  (within each 16x16 frag)
    const float qscale = 0.08838834764831845f;  // 128^-0.5 folded into Q
    const int b  = m0 / T_;
    const int t0 = m0 % T_;
#pragma unroll
    for (int rb = 0; rb < 2; ++rb) {
#pragma unroll
        for (int nb = 0; nb < 4; ++nb) {
            const int row0 = wr * 32 + rb * 16 + lk * 4;
            const int col  = wc * 64 + nb * 16 + lr;
            f32x4 aq = acc[0][rb][nb];
            f32x4 ak = acc[1][rb][nb];
            f32x4 av = acc[2][rb][nb];
#pragma unroll
            for (int r = 0; r < 4; ++r) {
                Q[(size_t)(m0 + row0 + r) * D_ + col] = f2bf(aq[r] * qscale);
                K[(size_t)(m0 + row0 + r) * D_ + col] = f2bf(ak[r]);
            }
            u16x4 pv;
#pragma unroll
            for (int r = 0; r < 4; ++r) pv[r] = f2bf(av[r]);
            *(u16x4*)&Vt[((size_t)b * D_ + col) * T_ + t0 + row0] = pv;
        }
    }
}

// ---------------------------------------------------------------------------
// Kernel 2: causal flash attention.
//   grid = 16 batches x 16 pairs; block = 256 thr (4 waves, 16 q-rows each).
//   Each block processes q-tile `pair` then q-tile `31-pair` (33 KV steps).
// ---------------------------------------------------------------------------
#define KSTR 136   // 128 + 8
#define VSTR 72    // 64 + 8
#define PSTR 72

__launch_bounds__(256, 1)
__global__ void attn_kernel(const unsigned short* __restrict__ Q, const unsigned short* __restrict__ K,
                            const unsigned short* __restrict__ Vt, float* __restrict__ out) {
    __shared__ unsigned short Klds[64 * KSTR];
    __shared__ unsigned short Vlds[128 * VSTR];
    __shared__ unsigned short Plds[4][16 * PSTR];

    const int tid  = threadIdx.x;
    const int lane = tid & 63;
    const int w    = tid >> 6;   // 0..3
    const int lr   = lane & 15;
    const int lk   = lane >> 4;

    const int batch = blockIdx.x >> 4;
    const int pair  = blockIdx.x & 15;

    const unsigned short* Qb = Q  + (size_t)batch * T_ * D_;
    const unsigned short* Kb = K  + (size_t)batch * T_ * D_;
    const unsigned short* Vb = Vt + (size_t)batch * D_ * T_;
    float* outb = out + (size_t)batch * T_ * D_;

    for (int half = 0; half < 2; ++half) {
        const int qt = (half == 0) ? pair : (31 - pair);
        const int q0 = qt * 64;
        const int qw = q0 + w * 16;   // this wave's 16 q-rows

        bf16x8 qf[4];
#pragma unroll
        for (int c = 0; c < 4; ++c)
            qf[c] = *(const bf16x8*)(Qb + (size_t)(qw + lr) * D_ + lk * 8 + c * 32);

        f32x4 o_acc[8] = {};
        float mrun[4] = {-1e30f, -1e30f, -1e30f, -1e30f};
        float lrun[4] = {0.f, 0.f, 0.f, 0.f};

        for (int kvt = 0; kvt <= qt; ++kvt) {
            // stage K tile [64][128] and Vt tile [128][64]
#pragma unroll
            for (int j = 0; j < 4; ++j) {
                int idx = j * 256 + tid;
                int r = idx >> 4, c8 = (idx & 15) * 8;
                bf16x8 v = *(const bf16x8*)(Kb + (size_t)(kvt * 64 + r) * D_ + c8);
                *(bf16x8*)&Klds[r * KSTR + c8] = v;
            }
#pragma unroll
            for (int j = 0; j < 4; ++j) {
                int idx = j * 256 + tid;
                int d = idx >> 3, c8 = (idx & 7) * 8;
                bf16x8 v = *(const bf16x8*)(Vb + (size_t)d * T_ + kvt * 64 + c8);
                *(bf16x8*)&Vlds[d * VSTR + c8] = v;
            }
            __syncthreads();

            // S = Q K^T  (16 q-rows x 64 kv)
            f32x4 s[4];
#pragma unroll
            for (int nb = 0; nb < 4; ++nb) {
                f32x4 a = {};
#pragma unroll
                for (int c = 0; c < 4; ++c) {
                    bf16x8 kf = *(bf16x8*)&Klds[(nb * 16 + lr) * KSTR + lk * 8 + c * 32];
                    a = __builtin_amdgcn_mfma_f32_16x16x32_bf16(qf[c], kf, a, 0, 0, 0);
                }
                s[nb] = a;
            }

            if (kvt == qt) {  // diagonal tile: causal mask
#pragma unroll
                for (int nb = 0; nb < 4; ++nb)
#pragma unroll
                    for (int r = 0; r < 4; ++r) {
                        int qg = qw + lk * 4 + r;
                        int kg = kvt * 64 + nb * 16 + lr;
                        if (kg > qg) s[nb][r] = -1e30f;
                    }
            }

            // online softmax (rows live across 16-lane groups)
            float scale_[4];
#pragma unroll
            for (int r = 0; r < 4; ++r) {
                float mx = fmaxf(fmaxf(s[0][r], s[1][r]), fmaxf(s[2][r], s[3][r]));
                mx = fmaxf(mx, __shfl_xor(mx, 1));
                mx = fmaxf(mx, __shfl_xor(mx, 2));
                mx = fmaxf(mx, __shfl_xor(mx, 4));
                mx = fmaxf(mx, __shfl_xor(mx, 8));
                float mnew = fmaxf(mrun[r], mx);
                scale_[r]  = __expf(mrun[r] - mnew);
                mrun[r]    = mnew;
                lrun[r]   *= scale_[r];
            }
#pragma unroll
            for (int db = 0; db < 8; ++db)
#pragma unroll
                for (int r = 0; r < 4; ++r) o_acc[db][r] *= scale_[r];

            // P = exp(S - m) -> bf16 via per-wave LDS region
#pragma unroll
            for (int nb = 0; nb < 4; ++nb)
#pragma unroll
                for (int r = 0; r < 4; ++r) {
                    float p = __expf(s[nb][r] - mrun[r]);
                    lrun[r] += p;
                    Plds[w][(lk * 4 + r) * PSTR + nb * 16 + lr] = f2bf(p);
                }
            asm volatile("s_waitcnt lgkmcnt(0)" ::: "memory");
            __builtin_amdgcn_sched_barrier(0);

            // O += P V
            bf16x8 pa[2];
#pragma unroll
            for (int c = 0; c < 2; ++c)
                pa[c] = *(bf16x8*)&Plds[w][lr * PSTR + lk * 8 + c * 32];
#pragma unroll
            for (int db = 0; db < 8; ++db) {
                f32x4 oo = o_acc[db];
#pragma unroll
                for (int c = 0; c < 2; ++c) {
                    bf16x8 vf = *(bf16x8*)&Vlds[(db * 16 + lr) * VSTR + lk * 8 + c * 32];
                    oo = __builtin_amdgcn_mfma_f32_16x16x32_bf16(pa[c], vf, oo, 0, 0, 0);
                }
                o_acc[db] = oo;
            }
            __syncthreads();
        }

        // epilogue: full row-sum reduce, normalize, store fp32
#pragma unroll
        for (int r = 0; r < 4; ++r) {
            float sgm = lrun[r];
            sgm += __shfl_xor(sgm, 1);
            sgm += __shfl_xor(sgm, 2);
            sgm += __shfl_xor(sgm, 4);
            sgm += __shfl_xor(sgm, 8);
            lrun[r] = 1.0f / sgm;
        }
#pragma unroll
        for (int db = 0; db < 8; ++db)
#pragma unroll
            for (int r = 0; r < 4; ++r)
                outb[(size_t)(qw + lk * 4 + r) * D_ + db * 16 + lr] = o_acc[db][r] * lrun[r];
    }
}

// ---------------------------------------------------------------------------
extern "C" void kernel_launch(void* const* d_in, const int* in_sizes, int n_in,
                              void* d_out, int out_size, void* d_ws, size_t ws_size,
                              hipStream_t stream) {
    const float* x  = (const float*)d_in[0];
    const float* Wq = (const float*)d_in[1];
    const float* Wk = (const float*)d_in[2];
    const float* Wv = (const float*)d_in[3];

    unsigned short* Wt  = (unsigned short*)d_ws;                          // 3*128*1024*2 = 768 KB
    unsigned short* Qw  = (unsigned short*)((char*)d_ws + (1 << 20));     // 8 MB
    unsigned short* Kw  = Qw + (size_t)M_ * D_;                           // 8 MB
    unsigned short* Vtw = Kw + (size_t)M_ * D_;                           // 8 MB

    hipLaunchKernelGGL(wt_kernel, dim3(1536), dim3(256), 0, stream, Wq, Wk, Wv, Wt);
    hipLaunchKernelGGL(qkv_kernel, dim3(256), dim3(512), 0, stream, x, Wt, Qw, Kw, Vtw);
    hipLaunchKernelGGL(attn_kernel, dim3(256), dim3(256), 0, stream, Qw, Kw, Vtw, (float*)d_out);
}

// Round 2
// 101.396 us; speedup vs baseline: 1.4808x; 1.4808x over previous
//
#include <hip/hip_runtime.h>
#include <hip/hip_bf16.h>

typedef short bf16x8 __attribute__((ext_vector_type(8)));
typedef float f32x4 __attribute__((ext_vector_type(4)));
typedef unsigned short u16x4 __attribute__((ext_vector_type(4)));

#define B_ 16
#define T_ 2048
#define C_ 1024
#define D_ 128
#define M_ (B_ * T_)

static __device__ __forceinline__ unsigned short f2bf(float f) {
    unsigned int u = __builtin_bit_cast(unsigned int, f);
    unsigned int r = (u + 0x7fffu + ((u >> 16) & 1u)) >> 16;
    return (unsigned short)r;
}

// ---------------------------------------------------------------------------
// Kernel 0: W [1024][128] fp32  ->  Wt [128][1024] bf16   (x3, concatenated)
// ---------------------------------------------------------------------------
__global__ void wt_kernel(const float* __restrict__ Wq, const float* __restrict__ Wk,
                          const float* __restrict__ Wv, unsigned short* __restrict__ Wt) {
    int idx = blockIdx.x * 256 + threadIdx.x;   // 3 * 131072 total
    int o   = idx >> 17;
    int rem = idx & 131071;
    int k   = rem >> 7;
    int n   = rem & 127;
    const float* W = (o == 0) ? Wq : (o == 1) ? Wk : Wv;
    Wt[o * (D_ * C_) + n * C_ + k] = f2bf(W[rem]);
}

// ---------------------------------------------------------------------------
// Kernel 1: fused QKV projection.  BM=128, BN=384 (Q|K|V), BK=64.
// 512 thr / 8 waves (2 row x 4 col); per wave 64x96 output.
// Double-buffered LDS, one barrier per K-step, loads(t+1) hidden under MFMA(t).
// ---------------------------------------------------------------------------
#define ASTR 68   // 64 + 4 bf16 pad
#define BSTR 68

__launch_bounds__(512, 1)
__global__ void qkv_kernel(const float* __restrict__ x, const unsigned short* __restrict__ Wt,
                           unsigned short* __restrict__ Q, unsigned short* __restrict__ K,
                           unsigned short* __restrict__ Vt) {
    __shared__ unsigned short Alds[2][128 * ASTR];   // 34.8 KB
    __shared__ unsigned short Blds[2][384 * BSTR];   // 104.4 KB

    const int tid  = threadIdx.x;
    const int lane = tid & 63;
    const int w    = tid >> 6;   // 0..7
    const int wr   = w >> 2;     // 0..1  (64-row group)
    const int wc   = w & 3;      // 0..3  (96-col group)
    const int lr   = lane & 15;
    const int lk   = lane >> 4;  // 0..3
    const int m0   = blockIdx.x * 128;

    // staging index maps (contiguous 16B granules per instruction)
    const int axr = tid >> 4;        // 0..31, +j*32   (A: 16 lanes per 64-float row)
    const int axc = (tid & 15) * 4;  // float col
    const int bxr = tid >> 3;        // 0..63, +j*64   (B: 8 lanes per 64-bf16 row)
    const int bxc = (tid & 7) * 8;   // bf16 col

    float4 ar[4];
    bf16x8 br[6];

    auto stage_load = [&](int k0) {
#pragma unroll
        for (int j = 0; j < 4; ++j)
            ar[j] = *(const float4*)(x + (size_t)(m0 + axr + j * 32) * C_ + k0 + axc);
#pragma unroll
        for (int j = 0; j < 6; ++j)
            br[j] = *(const bf16x8*)(Wt + (size_t)(bxr + j * 64) * C_ + k0 + bxc);
    };
    auto stage_write = [&](int buf) {
#pragma unroll
        for (int j = 0; j < 4; ++j) {
            u16x4 v;
            v[0] = f2bf(ar[j].x); v[1] = f2bf(ar[j].y);
            v[2] = f2bf(ar[j].z); v[3] = f2bf(ar[j].w);
            *(u16x4*)&Alds[buf][(axr + j * 32) * ASTR + axc] = v;
        }
#pragma unroll
        for (int j = 0; j < 6; ++j)
            *(bf16x8*)&Blds[buf][(bxr + j * 64) * BSTR + bxc] = br[j];
    };

    f32x4 acc[4][6] = {};

    auto compute = [&](int buf) {
#pragma unroll
        for (int kk = 0; kk < 2; ++kk) {
            bf16x8 a[4], b[6];
#pragma unroll
            for (int rb = 0; rb < 4; ++rb)
                a[rb] = *(bf16x8*)&Alds[buf][(wr * 64 + rb * 16 + lr) * ASTR + kk * 32 + lk * 8];
#pragma unroll
            for (int nb = 0; nb < 6; ++nb)
                b[nb] = *(bf16x8*)&Blds[buf][(wc * 96 + nb * 16 + lr) * BSTR + kk * 32 + lk * 8];
#pragma unroll
            for (int rb = 0; rb < 4; ++rb)
#pragma unroll
                for (int nb = 0; nb < 6; ++nb)
                    acc[rb][nb] = __builtin_amdgcn_mfma_f32_16x16x32_bf16(a[rb], b[nb], acc[rb][nb], 0, 0, 0);
        }
    };

    stage_load(0);
    stage_write(0);
    for (int t = 0; t < 16; ++t) {
        __syncthreads();                    // buf[t&1] ready; buf[(t+1)&1] free
        if (t < 15) stage_load((t + 1) * 64);
        compute(t & 1);
        if (t < 15) stage_write((t + 1) & 1);
    }

    // epilogue. D frag layout: row = lk*4 + r, col = lr
    const float qscale = 0.08838834764831845f;  // 128^-0.5 folded into Q
    const int b  = m0 / T_;
    const int t0 = m0 % T_;
#pragma unroll
    for (int rb = 0; rb < 4; ++rb) {
#pragma unroll
        for (int nb = 0; nb < 6; ++nb) {
            const int row0 = wr * 64 + rb * 16 + lk * 4;
            const int col  = wc * 96 + nb * 16 + lr;
            const int o    = col >> 7;
            const int d    = col & 127;
            f32x4 a = acc[rb][nb];
            if (o == 0) {
#pragma unroll
                for (int r = 0; r < 4; ++r)
                    Q[(size_t)(m0 + row0 + r) * D_ + d] = f2bf(a[r] * qscale);
            } else if (o == 1) {
#pragma unroll
                for (int r = 0; r < 4; ++r)
                    K[(size_t)(m0 + row0 + r) * D_ + d] = f2bf(a[r]);
            } else {
                u16x4 pv;
#pragma unroll
                for (int r = 0; r < 4; ++r) pv[r] = f2bf(a[r]);
                *(u16x4*)&Vt[((size_t)b * D_ + d) * T_ + t0 + row0] = pv;
            }
        }
    }
}

// ---------------------------------------------------------------------------
// Kernel 2: causal flash attention, double-buffered K/V staging.
//   grid = 16 batches x 16 pairs; block = 256 thr (4 waves, 16 q-rows each).
//   Each block processes q-tile `pair` then q-tile `31-pair` (33 KV steps).
// ---------------------------------------------------------------------------
#define KSTR 132   // 128 + 4
#define VSTR 68    // 64 + 4
#define PSTR 68

__launch_bounds__(256, 2)
__global__ void attn_kernel(const unsigned short* __restrict__ Q, const unsigned short* __restrict__ K,
                            const unsigned short* __restrict__ Vt, float* __restrict__ out) {
    __shared__ unsigned short Klds[2][64 * KSTR];    // 33.8 KB
    __shared__ unsigned short Vlds[2][128 * VSTR];   // 34.8 KB
    __shared__ unsigned short Plds[4][16 * PSTR];    // 8.7 KB

    const int tid  = threadIdx.x;
    const int lane = tid & 63;
    const int w    = tid >> 6;   // 0..3
    const int lr   = lane & 15;
    const int lk   = lane >> 4;

    const int batch = blockIdx.x >> 4;
    const int pair  = blockIdx.x & 15;

    const unsigned short* Qb = Q  + (size_t)batch * T_ * D_;
    const unsigned short* Kb = K  + (size_t)batch * T_ * D_;
    const unsigned short* Vb = Vt + (size_t)batch * D_ * T_;
    float* outb = out + (size_t)batch * T_ * D_;

    // staging maps
    const int kxr = tid >> 4;        // 0..15, +j*16  (K: 16 lanes per 128-bf16 row)
    const int kxc = (tid & 15) * 8;
    const int vxr = tid >> 3;        // 0..31, +j*32  (V: 8 lanes per 64-bf16 row)
    const int vxc = (tid & 7) * 8;

    bf16x8 kr[4], vr[4];
    auto kv_load = [&](int kvt) {
        const int kv0 = kvt * 64;
#pragma unroll
        for (int j = 0; j < 4; ++j)
            kr[j] = *(const bf16x8*)(Kb + (size_t)(kv0 + kxr + j * 16) * D_ + kxc);
#pragma unroll
        for (int j = 0; j < 4; ++j)
            vr[j] = *(const bf16x8*)(Vb + (size_t)(vxr + j * 32) * T_ + kv0 + vxc);
    };
    auto kv_write = [&](int buf) {
#pragma unroll
        for (int j = 0; j < 4; ++j)
            *(bf16x8*)&Klds[buf][(kxr + j * 16) * KSTR + kxc] = kr[j];
#pragma unroll
        for (int j = 0; j < 4; ++j)
            *(bf16x8*)&Vlds[buf][(vxr + j * 32) * VSTR + vxc] = vr[j];
    };

    for (int half = 0; half < 2; ++half) {
        const int qt = (half == 0) ? pair : (31 - pair);
        const int qw = qt * 64 + w * 16;   // this wave's 16 q-rows

        bf16x8 qf[4];
#pragma unroll
        for (int c = 0; c < 4; ++c)
            qf[c] = *(const bf16x8*)(Qb + (size_t)(qw + lr) * D_ + lk * 8 + c * 32);

        f32x4 o_acc[8] = {};
        float mrun[4] = {-1e30f, -1e30f, -1e30f, -1e30f};
        float lrun[4] = {0.f, 0.f, 0.f, 0.f};

        __syncthreads();            // previous half fully done with LDS
        kv_load(0);
        kv_write(0);

        for (int kvt = 0; kvt <= qt; ++kvt) {
            const int cur = kvt & 1;
            __syncthreads();        // buf[cur] ready; buf[cur^1] free
            if (kvt < qt) kv_load(kvt + 1);

            // S = Q K^T  (16 q-rows x 64 kv)
            f32x4 s[4];
#pragma unroll
            for (int nb = 0; nb < 4; ++nb) {
                f32x4 a = {};
#pragma unroll
                for (int c = 0; c < 4; ++c) {
                    bf16x8 kf = *(bf16x8*)&Klds[cur][(nb * 16 + lr) * KSTR + lk * 8 + c * 32];
                    a = __builtin_amdgcn_mfma_f32_16x16x32_bf16(qf[c], kf, a, 0, 0, 0);
                }
                s[nb] = a;
            }

            if (kvt == qt) {  // diagonal tile: causal mask
#pragma unroll
                for (int nb = 0; nb < 4; ++nb)
#pragma unroll
                    for (int r = 0; r < 4; ++r) {
                        int qg = qw + lk * 4 + r;
                        int kg = kvt * 64 + nb * 16 + lr;
                        if (kg > qg) s[nb][r] = -1e30f;
                    }
            }

            // online softmax (rows live across 16-lane groups)
            float scale_[4];
#pragma unroll
            for (int r = 0; r < 4; ++r) {
                float mx = fmaxf(fmaxf(s[0][r], s[1][r]), fmaxf(s[2][r], s[3][r]));
                mx = fmaxf(mx, __shfl_xor(mx, 1));
                mx = fmaxf(mx, __shfl_xor(mx, 2));
                mx = fmaxf(mx, __shfl_xor(mx, 4));
                mx = fmaxf(mx, __shfl_xor(mx, 8));
                float mnew = fmaxf(mrun[r], mx);
                scale_[r]  = __expf(mrun[r] - mnew);
                mrun[r]    = mnew;
                lrun[r]   *= scale_[r];
            }
#pragma unroll
            for (int db = 0; db < 8; ++db)
#pragma unroll
                for (int r = 0; r < 4; ++r) o_acc[db][r] *= scale_[r];

            // P = exp(S - m) -> bf16 via per-wave LDS region
#pragma unroll
            for (int nb = 0; nb < 4; ++nb)
#pragma unroll
                for (int r = 0; r < 4; ++r) {
                    float p = __expf(s[nb][r] - mrun[r]);
                    lrun[r] += p;
                    Plds[w][(lk * 4 + r) * PSTR + nb * 16 + lr] = f2bf(p);
                }
            asm volatile("s_waitcnt lgkmcnt(0)" ::: "memory");
            __builtin_amdgcn_sched_barrier(0);

            // O += P V
            bf16x8 pa[2];
#pragma unroll
            for (int c = 0; c < 2; ++c)
                pa[c] = *(bf16x8*)&Plds[w][lr * PSTR + lk * 8 + c * 32];
#pragma unroll
            for (int db = 0; db < 8; ++db) {
                f32x4 oo = o_acc[db];
#pragma unroll
                for (int c = 0; c < 2; ++c) {
                    bf16x8 vf = *(bf16x8*)&Vlds[cur][(db * 16 + lr) * VSTR + lk * 8 + c * 32];
                    oo = __builtin_amdgcn_mfma_f32_16x16x32_bf16(pa[c], vf, oo, 0, 0, 0);
                }
                o_acc[db] = oo;
            }

            if (kvt < qt) kv_write(cur ^ 1);
        }

        // epilogue: full row-sum reduce, normalize, store fp32
#pragma unroll
        for (int r = 0; r < 4; ++r) {
            float sgm = lrun[r];
            sgm += __shfl_xor(sgm, 1);
            sgm += __shfl_xor(sgm, 2);
            sgm += __shfl_xor(sgm, 4);
            sgm += __shfl_xor(sgm, 8);
            lrun[r] = 1.0f / sgm;
        }
#pragma unroll
        for (int db = 0; db < 8; ++db)
#pragma unroll
            for (int r = 0; r < 4; ++r)
                outb[(size_t)(qw + lk * 4 + r) * D_ + db * 16 + lr] = o_acc[db][r] * lrun[r];
    }
}

// ---------------------------------------------------------------------------
extern "C" void kernel_launch(void* const* d_in, const int* in_sizes, int n_in,
                              void* d_out, int out_size, void* d_ws, size_t ws_size,
                              hipStream_t stream) {
    const float* x  = (const float*)d_in[0];
    const float* Wq = (const float*)d_in[1];
    const float* Wk = (const float*)d_in[2];
    const float* Wv = (const float*)d_in[3];

    unsigned short* Wt  = (unsigned short*)d_ws;                          // 768 KB
    unsigned short* Qw  = (unsigned short*)((char*)d_ws + (1 << 20));     // 8 MB
    unsigned short* Kw  = Qw + (size_t)M_ * D_;                           // 8 MB
    unsigned short* Vtw = Kw + (size_t)M_ * D_;                           // 8 MB

    hipLaunchKernelGGL(wt_kernel, dim3(1536), dim3(256), 0, stream, Wq, Wk, Wv, Wt);
    hipLaunchKernelGGL(qkv_kernel, dim3(256), dim3(512), 0, stream, x, Wt, Qw, Kw, Vtw);
    hipLaunchKernelGGL(attn_kernel, dim3(256), dim3(256), 0, stream, Qw, Kw, Vtw, (float*)d_out);
}